// Round 3
// baseline (141.032 us; speedup 1.0000x reference)
//
#include <hip/hip_runtime.h>
#include <hip/hip_bf16.h>
#include <stdint.h>

#define AS1 __attribute__((address_space(1)))
#define AS3 __attribute__((address_space(3)))

typedef short  s16x8  __attribute__((ext_vector_type(8)));
typedef float  f32x16 __attribute__((ext_vector_type(16)));
typedef unsigned int u32;

static constexpr int DDIM = 256;
static constexpr float TEN_LOG2E = 14.4269504088896340736f; // 10 * log2(e)

// ---------------- Kernel 1: row-normalize p = [z_i; z_j], cast to bf16 ----------------
// Also zero-inits row_s[8192] (blocks 0..7) and out[0] (block 0).
__global__ __launch_bounds__(256) void normalize_bf16_kernel(
    const float* __restrict__ zi, const float* __restrict__ zj,
    ushort* __restrict__ pn, float* __restrict__ row_s, float* __restrict__ out)
{
    if (blockIdx.x < 8) {
        ((float4*)row_s)[blockIdx.x * 256 + threadIdx.x] = (float4){0.f, 0.f, 0.f, 0.f};
        if (blockIdx.x == 0 && threadIdx.x == 0) out[0] = 0.0f;
    }

    const int row  = blockIdx.x * 4 + (threadIdx.x >> 6);
    const int lane = threadIdx.x & 63;
    const float* src = (row < 4096) ? (zi + (size_t)row * DDIM)
                                    : (zj + (size_t)(row - 4096) * DDIM);
    float4 v = ((const float4*)src)[lane];
    float ss = v.x * v.x + v.y * v.y + v.z * v.z + v.w * v.w;
    #pragma unroll
    for (int off = 32; off > 0; off >>= 1) ss += __shfl_xor(ss, off, 64);
    const float inv = 1.0f / fmaxf(sqrtf(ss), 1e-8f);

    ushort4 o;
    o.x = __builtin_bit_cast(unsigned short, __float2bfloat16(v.x * inv));
    o.y = __builtin_bit_cast(unsigned short, __float2bfloat16(v.y * inv));
    o.z = __builtin_bit_cast(unsigned short, __float2bfloat16(v.z * inv));
    o.w = __builtin_bit_cast(unsigned short, __float2bfloat16(v.w * inv));
    ((ushort4*)(pn + (size_t)row * DDIM))[lane] = o;
}

// ---------------- Kernel 2: upper-triangle 128x128 Gram tiles, fused exp sums ---------
// 2080 blocks = 64*65/2 upper-triangle tiles. Block 256 threads = 4 waves, each wave a
// 64x64 sub-tile via 32x32x16 MFMA (acc 2x2 f32x16). K=256 staged in two 64KB phases
// (A panel 128x128k + B panel 128x128k), XOR-swizzled to kill LDS bank conflicts.
// Off-diagonal tiles: row-sums -> row_s[r0+..], col-sums -> row_s[c0+..] (symmetry).
// Diagonal tiles: full tile computed in-place; only row-sums, diag masked.
__global__ __launch_bounds__(256, 2) void simexp_kernel(
    const ushort* __restrict__ pn,
    float* __restrict__ row_s,
    float* __restrict__ pos_out)
{
    __shared__ __align__(16) ushort ldsA[128 * 128];
    __shared__ __align__(16) ushort ldsB[128 * 128];

    const int tid  = threadIdx.x;
    const int w    = tid >> 6;
    const int lane = tid & 63;
    const int l31  = lane & 31;
    const int khi  = lane >> 5;          // 0/1: which K-octet of the MFMA operand
    const int wm   = (w & 1) * 64;       // wave row offset
    const int wn   = (w >> 1) * 64;      // wave col offset

    // ---- upper-triangle decode: block b -> (ti, tj), ti <= tj ----
    const int b = blockIdx.x;
    int ti = (int)(64.5f - sqrtf(64.5f * 64.5f - 2.0f * (float)b));
    while ((ti + 1) * 64 - ((ti + 1) * ti) / 2 <= b) ++ti;
    while (ti * 64 - (ti * (ti - 1)) / 2 > b) --ti;
    const int tj = ti + (b - (ti * 64 - (ti * (ti - 1)) / 2));
    const int r0 = ti * 128, c0 = tj * 128;
    const bool diag  = (ti == tj);
    const bool ptile = (tj == ti + 32);  // contains positive-pair diagonal

    // staging role: waves 0,1 -> A panel rows, waves 2,3 -> B panel rows
    const ushort* gpanel = (w < 2) ? (pn + (size_t)r0 * DDIM) : (pn + (size_t)c0 * DDIM);
    ushort* lpanel = (w < 2) ? ldsA : ldsB;
    const int wrb      = (w & 1) * 64;   // 64-row half of panel this wave stages
    const int srow_in4 = lane >> 4;      // 0..3 (4 rows per 64-lane issue)
    const int spchunk  = lane & 15;      // phys 16B chunk within row (16 chunks/row)

    f32x16 acc[2][2];
    #pragma unroll
    for (int mi = 0; mi < 2; ++mi)
        #pragma unroll
        for (int ni = 0; ni < 2; ++ni)
            #pragma unroll
            for (int r = 0; r < 16; ++r) acc[mi][ni][r] = 0.0f;

    #pragma unroll
    for (int half = 0; half < 2; ++half) {
        if (half) __syncthreads();   // prior compute done before overwriting panels
        // ---- stage 64KB: each lane 16 x global_load_lds(16B); LDS slot is fixed
        //      (base + lane*16), so the lane fetches the global chunk that belongs
        //      at its swizzled slot: phys = chunk ^ (row & 7).
        #pragma unroll 4
        for (int i = 0; i < 16; ++i) {
            const int R  = wrb + i * 4 + srow_in4;          // row within panel
            const int cg = spchunk ^ (R & 7);               // logical chunk to fetch
            const ushort* g = gpanel + (size_t)R * DDIM + half * 128 + cg * 8;
            ushort* l = lpanel + (wrb + i * 4) * 128;       // wave-uniform base
            __builtin_amdgcn_global_load_lds((const AS1 u32*)g, (AS3 u32*)l, 16, 0, 0);
        }
        __syncthreads();

        // ---- compute: 8 K-steps of 16 over this half's panels, no barriers ----
        #pragma unroll
        for (int kt = 0; kt < 8; ++kt) {
            s16x8 af[2], bfr[2];
            #pragma unroll
            for (int mi = 0; mi < 2; ++mi) {
                const int R = wm + mi * 32 + l31;
                const int p = (kt * 2 + khi) ^ (R & 7);
                af[mi] = *(const s16x8*)(ldsA + R * 128 + p * 8);
            }
            #pragma unroll
            for (int ni = 0; ni < 2; ++ni) {
                const int R = wn + ni * 32 + l31;
                const int p = (kt * 2 + khi) ^ (R & 7);
                bfr[ni] = *(const s16x8*)(ldsB + R * 128 + p * 8);
            }
            #pragma unroll
            for (int mi = 0; mi < 2; ++mi)
                #pragma unroll
                for (int ni = 0; ni < 2; ++ni)
                    acc[mi][ni] = __builtin_amdgcn_mfma_f32_32x32x16_bf16(
                        af[mi], bfr[ni], acc[mi][ni], 0, 0, 0);
        }
    }

    // ---- epilogue: exp, diag mask, positive extraction, row/col sums ----
    // C/D layout (32x32): col = lane&31, row = (r&3) + 8*(r>>2) + 4*(lane>>5)
    float rsum[2][16];
    float csum[2] = {0.0f, 0.0f};
    #pragma unroll
    for (int mi = 0; mi < 2; ++mi)
        #pragma unroll
        for (int r = 0; r < 16; ++r) rsum[mi][r] = 0.0f;

    #pragma unroll
    for (int mi = 0; mi < 2; ++mi)
        #pragma unroll
        for (int ni = 0; ni < 2; ++ni)
            #pragma unroll
            for (int r = 0; r < 16; ++r) {
                const int lr = wm + mi * 32 + (r & 3) + 8 * (r >> 2) + 4 * khi;
                const int lc = wn + ni * 32 + l31;
                float e = exp2f(acc[mi][ni][r] * TEN_LOG2E);
                if (diag && lr == lc) e = 0.0f;          // mask self-similarity
                rsum[mi][r] += e;
                csum[ni]    += e;
                if (ptile && lr == lc) {                 // positive pair: c = r + 4096
                    const float v = acc[mi][ni][r] * 10.0f;
                    pos_out[r0 + lr] = v;
                    pos_out[c0 + lr] = v;
                }
            }

    // row sums: reduce across the 32 lanes sharing each row set
    #pragma unroll
    for (int mi = 0; mi < 2; ++mi)
        #pragma unroll
        for (int r = 0; r < 16; ++r) {
            float v = rsum[mi][r];
            v += __shfl_xor(v, 1, 64);
            v += __shfl_xor(v, 2, 64);
            v += __shfl_xor(v, 4, 64);
            v += __shfl_xor(v, 8, 64);
            v += __shfl_xor(v, 16, 64);
            rsum[mi][r] = v;
        }
    if (l31 == 0) {
        #pragma unroll
        for (int mi = 0; mi < 2; ++mi)
            #pragma unroll
            for (int r = 0; r < 16; ++r) {
                const int lr = wm + mi * 32 + (r & 3) + 8 * (r >> 2) + 4 * khi;
                atomicAdd(&row_s[r0 + lr], rsum[mi][r]);
            }
    }
    // col sums (symmetric contribution) — skip on diagonal tiles (already counted)
    if (!diag) {
        #pragma unroll
        for (int ni = 0; ni < 2; ++ni) {
            float v = csum[ni];
            v += __shfl_xor(v, 32, 64);
            if (khi == 0)
                atomicAdd(&row_s[c0 + wn + ni * 32 + l31], v);
        }
    }
}

// ---------------- Kernel 3: finalize loss ----------------
__global__ __launch_bounds__(256) void finalize_kernel(
    const float* __restrict__ row_s, const float* __restrict__ pos,
    float* __restrict__ out)
{
    const int i = blockIdx.x * 256 + threadIdx.x;   // float4 index, 2048 total
    float4 s = ((const float4*)row_s)[i];
    float4 p = ((const float4*)pos)[i];
    float local = (__logf(s.x) - p.x) + (__logf(s.y) - p.y)
                + (__logf(s.z) - p.z) + (__logf(s.w) - p.w);
    #pragma unroll
    for (int off = 32; off > 0; off >>= 1) local += __shfl_xor(local, off, 64);
    __shared__ float red[4];
    if ((threadIdx.x & 63) == 0) red[threadIdx.x >> 6] = local;
    __syncthreads();
    if (threadIdx.x == 0)
        atomicAdd(out, (red[0] + red[1] + red[2] + red[3]) * (1.0f / 8192.0f));
}

// ---------------- Launch ----------------
extern "C" void kernel_launch(void* const* d_in, const int* in_sizes, int n_in,
                              void* d_out, int out_size, void* d_ws, size_t ws_size,
                              hipStream_t stream)
{
    const float* zi = (const float*)d_in[0];
    const float* zj = (const float*)d_in[1];

    ushort* pn   = (ushort*)d_ws;                                    // 4 MB bf16 normalized rows
    float* row_s = (float*)((char*)d_ws + (4u << 20));               // 8192 fp32
    float* pos   = (float*)((char*)d_ws + (4u << 20) + (32u << 10)); // 8192 fp32
    float* out   = (float*)d_out;

    hipLaunchKernelGGL(normalize_bf16_kernel, dim3(2048), dim3(256), 0, stream,
                       zi, zj, pn, row_s, out);
    hipLaunchKernelGGL(simexp_kernel, dim3(2080), dim3(256), 0, stream, pn, row_s, pos);
    hipLaunchKernelGGL(finalize_kernel, dim3(8), dim3(256), 0, stream, row_s, pos, out);
}